// Round 20
// baseline (117.672 us; speedup 1.0000x reference)
//
#include <hip/hip_runtime.h>

#define N_NODES 100000
#define N_EDGES 3200000
#define F_IN    128
#define HIDDEN  16
#define F_OUT   2

#define BSZ     256                  // nodes per bucket
#define NB      391                  // ceil(N_NODES / BSZ)
#define NPAD    (NB * BSZ)           // 100096 padded node rows
#define G       800                  // edge-partition blocks for hist/scatter
#define EPB     (N_EDGES / G)        // 4000 edges per partition (exact, even)
#define DUMMY_E 100000u              // zeroed pad row used for clamped slots
#define STCAP   8768                 // LDS stage capacity (mean 8192 + 6.4 sigma)

typedef float  f32x4 __attribute__((ext_vector_type(4)));
typedef float  f32x2 __attribute__((ext_vector_type(2)));
typedef _Float16 half8 __attribute__((ext_vector_type(8)));

// ---------- P1: per-partition bucket histogram (r12-proven) ----------
__global__ __launch_bounds__(256) void k_hist(const int* __restrict__ dst,
                                              unsigned* __restrict__ blockHist) {
    __shared__ unsigned h0[NB];
    __shared__ unsigned h1[NB];
    int t = threadIdx.x, g = blockIdx.x;
    for (int i = t; i < NB; i += 256) { h0[i] = 0u; h1[i] = 0u; }
    __syncthreads();
    const int2* d2 = (const int2*)(dst + g * EPB);
    unsigned* myh = (t & 1) ? h1 : h0;
    for (int i = t; i < EPB / 2; i += 256) {
        int2 v = d2[i];
        atomicAdd(&myh[(unsigned)v.x >> 8], 1u);
        atomicAdd(&myh[(unsigned)v.y >> 8], 1u);
    }
    __syncthreads();
    for (int i = t; i < NB; i += 256) blockHist[i * G + g] = h0[i] + h1[i];
}

// ---------- P2: per-bucket exclusive scan over partitions (r12-proven) ----------
__global__ __launch_bounds__(1024) void k_scan_blocks(unsigned* __restrict__ blockHist,
                                                      unsigned* __restrict__ total) {
    __shared__ unsigned s[1024];
    int b = blockIdx.x, t = threadIdx.x;
    unsigned v = (t < G) ? blockHist[b * G + t] : 0u;
    s[t] = v;
    __syncthreads();
    for (int off = 1; off < 1024; off <<= 1) {
        unsigned xv = (t >= off) ? s[t - off] : 0u;
        __syncthreads();
        s[t] += xv;
        __syncthreads();
    }
    if (t < G) blockHist[b * G + t] = s[t] - v;
    if (t == 1023) total[b] = s[t];
}

// ---------- P2c: exclusive scan of bucket totals (r12-proven) ----------
__global__ __launch_bounds__(512) void k_scan_buckets(const unsigned* __restrict__ total,
                                                      unsigned* __restrict__ bucketBase,
                                                      int* __restrict__ rowstart) {
    __shared__ unsigned s[512];
    int t = threadIdx.x;
    unsigned v = (t < NB) ? total[t] : 0u;
    s[t] = v;
    __syncthreads();
    for (int off = 1; off < 512; off <<= 1) {
        unsigned xv = (t >= off) ? s[t - off] : 0u;
        __syncthreads();
        s[t] += xv;
        __syncthreads();
    }
    if (t < NB) bucketBase[t] = s[t] - v;
    if (t == 511) {
        bucketBase[NB] = s[t];                 // == N_EDGES
        rowstart[N_NODES] = (int)s[t];
    }
}

// ---------- P3: LDS counting-sort scatter (r12-proven) ----------
// entry: (dst & 255) << 17 | src ; LDS ~31.3 KB -> 5 blocks/CU
__global__ __launch_bounds__(256) void k_scatter(const int* __restrict__ src,
                                                 const int* __restrict__ dst,
                                                 const unsigned* __restrict__ blockHist,
                                                 const unsigned* __restrict__ bucketBase,
                                                 unsigned* __restrict__ adj) {
    __shared__ unsigned stage[EPB];            // 16.0 KB
    __shared__ unsigned short stage_b[EPB];    // 8.0 KB
    __shared__ unsigned hist[NB];              // cursor
    __shared__ unsigned h1[NB];                // sub-hist
    __shared__ unsigned lstart[NB];
    __shared__ unsigned gbase[NB];
    __shared__ unsigned ssum[256];
    int t = threadIdx.x, g = blockIdx.x;
    for (int i = t; i < NB; i += 256) {
        hist[i] = 0u; h1[i] = 0u;
        gbase[i] = bucketBase[i] + blockHist[i * G + g];
    }
    __syncthreads();
    const int2* s2 = (const int2*)(src + g * EPB);
    const int2* d2 = (const int2*)(dst + g * EPB);
    unsigned* myh = (t & 1) ? h1 : hist;
    for (int i = t; i < EPB / 2; i += 256) {
        int2 v = d2[i];
        atomicAdd(&myh[(unsigned)v.x >> 8], 1u);
        atomicAdd(&myh[(unsigned)v.y >> 8], 1u);
    }
    __syncthreads();
    int i0 = t * 2;
    unsigned v0 = (i0 + 0 < NB) ? hist[i0 + 0] + h1[i0 + 0] : 0u;
    unsigned v1 = (i0 + 1 < NB) ? hist[i0 + 1] + h1[i0 + 1] : 0u;
    unsigned my = v0 + v1;
    ssum[t] = my;
    __syncthreads();
    for (int off = 1; off < 256; off <<= 1) {
        unsigned xv = (t >= off) ? ssum[t - off] : 0u;
        __syncthreads();
        ssum[t] += xv;
        __syncthreads();
    }
    unsigned e0 = ssum[t] - my;
    __syncthreads();
    unsigned e1 = e0 + v0;
    if (i0 + 0 < NB) { lstart[i0 + 0] = e0; hist[i0 + 0] = e0; }
    if (i0 + 1 < NB) { lstart[i0 + 1] = e1; hist[i0 + 1] = e1; }
    __syncthreads();
    for (int i = t; i < EPB / 2; i += 256) {
        int2 sv = s2[i], dv = d2[i];
        unsigned bkt0 = (unsigned)dv.x >> 8;
        unsigned pos0 = atomicAdd(&hist[bkt0], 1u);
        stage[pos0] = ((unsigned)(dv.x & 255) << 17) | (unsigned)sv.x;
        stage_b[pos0] = (unsigned short)bkt0;
        unsigned bkt1 = (unsigned)dv.y >> 8;
        unsigned pos1 = atomicAdd(&hist[bkt1], 1u);
        stage[pos1] = ((unsigned)(dv.y & 255) << 17) | (unsigned)sv.y;
        stage_b[pos1] = (unsigned short)bkt1;
    }
    __syncthreads();
    for (int j = t; j < EPB; j += 256) {
        unsigned bkt = stage_b[j];
        adj[gbase[bkt] + (j - lstart[bkt])] = stage[j];
    }
}

// ---------- P4: in-bucket counting sort IN PLACE + FUSED mm1 ----------
// Single global read: bucket -> LDS stage; histogram from LDS; permute
// LDS -> adj in place (CSR src-only). 4-way privatized hist/cursors.
__global__ __launch_bounds__(512) void k_sortmm(unsigned* __restrict__ adj,
                                                const unsigned* __restrict__ bucketBase,
                                                const float* __restrict__ x,
                                                const float* __restrict__ W1,
                                                int* __restrict__ rowstart,
                                                float* __restrict__ dinv,
                                                char* __restrict__ hs) {
    __shared__ float sW[F_IN * HIDDEN];        // 8 KB
    __shared__ unsigned stage[STCAP];          // 34.25 KB raw bucket entries
    __shared__ unsigned hist4[4][BSZ];         // 4 KB privatized hist
    __shared__ unsigned cur4[4][BSZ];          // 4 KB privatized cursors
    __shared__ unsigned sc[BSZ];               // 1 KB scan
    __shared__ float sdinv[BSZ];               // 1 KB
    int b = blockIdx.x, t = threadIdx.x;
    int sub = t >> 7;                           // wave-pair id 0..3
    for (int i = t; i < F_IN * HIDDEN; i += 512) sW[i] = W1[i];
    for (int i = t; i < 4 * BSZ; i += 512) ((unsigned*)hist4)[i] = 0u;
    __syncthreads();
    int e0 = (int)bucketBase[b], e1 = (int)bucketBase[b + 1];
    int len = e1 - e0;
    // phase 1: single coalesced global read -> LDS stage + privatized histogram
    for (int i = t; i < len; i += 512) {
        unsigned v = adj[e0 + i];
        stage[i] = v;
        atomicAdd(&hist4[sub][v >> 17], 1u);
    }
    __syncthreads();
    unsigned d0 = 0, d1 = 0, d2 = 0, d3 = 0, deg = 0;
    if (t < BSZ) {
        d0 = hist4[0][t]; d1 = hist4[1][t]; d2 = hist4[2][t]; d3 = hist4[3][t];
        deg = d0 + d1 + d2 + d3;
        sc[t] = deg;
    }
    __syncthreads();
    for (int off = 1; off < BSZ; off <<= 1) {
        unsigned a = 0;
        if (t < BSZ && t >= off) a = sc[t - off];
        __syncthreads();
        if (t < BSZ) sc[t] += a;
        __syncthreads();
    }
    if (t < BSZ) {
        unsigned excl = sc[t] - deg;
        cur4[0][t] = excl;
        cur4[1][t] = excl + d0;
        cur4[2][t] = excl + d0 + d1;
        cur4[3][t] = excl + d0 + d1 + d2;
        float dv = rsqrtf((float)(deg + 1u));
        sdinv[t] = dv;
        int node = b * BSZ + t;
        if (node < N_NODES) {
            rowstart[node] = e0 + (int)excl;
            dinv[node] = dv;
        }
    }
    __syncthreads();
    // phase 2: permute LDS -> adj in place (whole bucket is in LDS; safe)
    for (int i = t; i < len; i += 512) {
        unsigned v = stage[i];
        unsigned pos = atomicAdd(&cur4[sub][v >> 17], 1u);
        adj[e0 + (int)pos] = v & 0x1FFFFu;
    }
    // phase 3: fused mm1 (r15 register version): 2 lanes/node, 64 f-values each
    int nl = t >> 1, half = t & 1;
    int node = b * BSZ + nl;
    if (node >= N_NODES) {                     // zero pad rows incl. DUMMY row
        half8 hz = {(_Float16)0.f, (_Float16)0.f, (_Float16)0.f, (_Float16)0.f,
                    (_Float16)0.f, (_Float16)0.f, (_Float16)0.f, (_Float16)0.f};
        if (node < NPAD) *(half8*)(hs + (size_t)node * 32 + half * 16) = hz;
        return;
    }
    const f32x4* xr = (const f32x4*)(x + (size_t)node * F_IN + half * 64);
    const f32x4* wv = (const f32x4*)sW;
    f32x4 a0 = {0.f,0.f,0.f,0.f}, a1 = a0, a2 = a0, a3 = a0;
    #pragma unroll 4
    for (int k = 0; k < 16; ++k) {
        f32x4 xq = xr[k];
        int f0 = (half << 6) + (k << 2);
        #pragma unroll
        for (int j = 0; j < 4; ++j) {
            float xv = xq[j];
            const f32x4* wr = wv + (size_t)(f0 + j) * 4;
            a0 += xv * wr[0];
            a1 += xv * wr[1];
            a2 += xv * wr[2];
            a3 += xv * wr[3];
        }
    }
    a0[0] += __shfl_xor(a0[0], 1); a0[1] += __shfl_xor(a0[1], 1);
    a0[2] += __shfl_xor(a0[2], 1); a0[3] += __shfl_xor(a0[3], 1);
    a1[0] += __shfl_xor(a1[0], 1); a1[1] += __shfl_xor(a1[1], 1);
    a1[2] += __shfl_xor(a1[2], 1); a1[3] += __shfl_xor(a1[3], 1);
    a2[0] += __shfl_xor(a2[0], 1); a2[1] += __shfl_xor(a2[1], 1);
    a2[2] += __shfl_xor(a2[2], 1); a2[3] += __shfl_xor(a2[3], 1);
    a3[0] += __shfl_xor(a3[0], 1); a3[1] += __shfl_xor(a3[1], 1);
    a3[2] += __shfl_xor(a3[2], 1); a3[3] += __shfl_xor(a3[3], 1);
    float dv = sdinv[nl];
    f32x4 u = half ? a2 : a0;
    f32x4 v2 = half ? a3 : a1;
    half8 hh;
    hh[0] = (_Float16)(u[0] * dv);  hh[1] = (_Float16)(u[1] * dv);
    hh[2] = (_Float16)(u[2] * dv);  hh[3] = (_Float16)(u[3] * dv);
    hh[4] = (_Float16)(v2[0] * dv); hh[5] = (_Float16)(v2[1] * dv);
    hh[6] = (_Float16)(v2[2] * dv); hh[7] = (_Float16)(v2[3] * dv);
    *(half8*)(hs + (size_t)node * 32 + half * 16) = hh;
}

// ---------- layer-1 aggregation + FUSED layer-2 matmul (r12-proven) ----------
__global__ __launch_bounds__(256) void k_agg1(const unsigned* __restrict__ adj2,
                                              const int* __restrict__ rowstart,
                                              const char* __restrict__ hs,
                                              const float* __restrict__ dinv,
                                              const float* __restrict__ b1,
                                              const float* __restrict__ W2,
                                              float2* __restrict__ hs2) {
    int g = blockIdx.x * 256 + threadIdx.x;
    int node = g >> 1, le = g & 1;
    if (node >= N_NODES) {                     // zero pad rows incl. DUMMY
        if (le == 0 && node < NPAD) { float2 z = {0.f, 0.f}; hs2[node] = z; }
        return;
    }
    int rs = rowstart[node], re = rowstart[node + 1];
    unsigned le16 = (unsigned)le * 16u;
    unsigned dummy_off = DUMMY_E * 32u + le16;

    float a0 = 0.f, a1 = 0.f, a2 = 0.f, a3 = 0.f, a4 = 0.f, a5 = 0.f, a6 = 0.f, a7 = 0.f;
    f32x4 w0, w1, w2, w3, w4, w5, w6, w7;

#define GL1(dst, o) asm volatile("global_load_dwordx4 %0, %1, %2" \
    : "=v"(dst) : "v"(o), "s"(hs) : "memory");
#define AC1(w_) { half8 h8; __builtin_memcpy(&h8, &w_, 16); \
    a0 += (float)h8[0]; a1 += (float)h8[1]; a2 += (float)h8[2]; a3 += (float)h8[3]; \
    a4 += (float)h8[4]; a5 += (float)h8[5]; a6 += (float)h8[6]; a7 += (float)h8[7]; }

    for (int bs = rs; bs < re; bs += 8) {
        const unsigned* ap = adj2 + bs;        // adj padded by 8 -> safe reads
        unsigned j0 = ap[0], j1 = ap[1], j2 = ap[2], j3 = ap[3];
        unsigned j4 = ap[4], j5 = ap[5], j6 = ap[6], j7 = ap[7];
        unsigned o0 = (bs + 0 < re) ? (j0 << 5) + le16 : dummy_off;
        unsigned o1 = (bs + 1 < re) ? (j1 << 5) + le16 : dummy_off;
        unsigned o2 = (bs + 2 < re) ? (j2 << 5) + le16 : dummy_off;
        unsigned o3 = (bs + 3 < re) ? (j3 << 5) + le16 : dummy_off;
        unsigned o4 = (bs + 4 < re) ? (j4 << 5) + le16 : dummy_off;
        unsigned o5 = (bs + 5 < re) ? (j5 << 5) + le16 : dummy_off;
        unsigned o6 = (bs + 6 < re) ? (j6 << 5) + le16 : dummy_off;
        unsigned o7 = (bs + 7 < re) ? (j7 << 5) + le16 : dummy_off;
        GL1(w0, o0) GL1(w1, o1) GL1(w2, o2) GL1(w3, o3)
        GL1(w4, o4) GL1(w5, o5) GL1(w6, o6) GL1(w7, o7)
        asm volatile("s_waitcnt vmcnt(0)" ::: "memory");
        __builtin_amdgcn_sched_barrier(0);
        AC1(w0) AC1(w1) AC1(w2) AC1(w3) AC1(w4) AC1(w5) AC1(w6) AC1(w7)
    }
    const _Float16* selfrow = (const _Float16*)(hs + (size_t)node * 32 + le16);
    float dv = dinv[node];
    float q0 = dv * (a0 + (float)selfrow[0]), q1 = dv * (a1 + (float)selfrow[1]);
    float q2 = dv * (a2 + (float)selfrow[2]), q3 = dv * (a3 + (float)selfrow[3]);
    float q4 = dv * (a4 + (float)selfrow[4]), q5 = dv * (a5 + (float)selfrow[5]);
    float q6 = dv * (a6 + (float)selfrow[6]), q7 = dv * (a7 + (float)selfrow[7]);
    const float4* b1v = (const float4*)(b1 + le * 8);
    float4 ba = b1v[0], bb = b1v[1];
    const float4* w2v = (const float4*)(W2 + le * 16);
    float4 wA = w2v[0], wB = w2v[1], wC = w2v[2], wD = w2v[3];
    float p0 = 0.f, p1 = 0.f, r;
    r = fmaxf(q0 + ba.x, 0.f); p0 = fmaf(r, wA.x, p0); p1 = fmaf(r, wA.y, p1);
    r = fmaxf(q1 + ba.y, 0.f); p0 = fmaf(r, wA.z, p0); p1 = fmaf(r, wA.w, p1);
    r = fmaxf(q2 + ba.z, 0.f); p0 = fmaf(r, wB.x, p0); p1 = fmaf(r, wB.y, p1);
    r = fmaxf(q3 + ba.w, 0.f); p0 = fmaf(r, wB.z, p0); p1 = fmaf(r, wB.w, p1);
    r = fmaxf(q4 + bb.x, 0.f); p0 = fmaf(r, wC.x, p0); p1 = fmaf(r, wC.y, p1);
    r = fmaxf(q5 + bb.y, 0.f); p0 = fmaf(r, wC.z, p0); p1 = fmaf(r, wC.w, p1);
    r = fmaxf(q6 + bb.z, 0.f); p0 = fmaf(r, wD.x, p0); p1 = fmaf(r, wD.y, p1);
    r = fmaxf(q7 + bb.w, 0.f); p0 = fmaf(r, wD.z, p0); p1 = fmaf(r, wD.w, p1);
    p0 += __shfl_xor(p0, 1);
    p1 += __shfl_xor(p1, 1);
    if (le == 0) {
        float2 h2; h2.x = p0 * dv; h2.y = p1 * dv;
        hs2[node] = h2;
    }
}

// ---------- layer-2 aggregation + finalize (r12-proven) ----------
__global__ __launch_bounds__(256) void k_agg2(const unsigned* __restrict__ adj2,
                                              const int* __restrict__ rowstart,
                                              const char* __restrict__ hs2,
                                              const float* __restrict__ dinv,
                                              const float* __restrict__ b2,
                                              float2* __restrict__ out) {
    int node = blockIdx.x * 256 + threadIdx.x;
    if (node >= N_NODES) return;
    int rs = rowstart[node], re = rowstart[node + 1];
    unsigned dummy_off = DUMMY_E * 8u;

    float a0 = 0.f, a1 = 0.f;
    f32x2 w0, w1, w2, w3, w4, w5, w6, w7;

#define GL2(dst, o) asm volatile("global_load_dwordx2 %0, %1, %2" \
    : "=v"(dst) : "v"(o), "s"(hs2) : "memory");

    for (int bs = rs; bs < re; bs += 8) {
        const unsigned* ap = adj2 + bs;
        unsigned j0 = ap[0], j1 = ap[1], j2 = ap[2], j3 = ap[3];
        unsigned j4 = ap[4], j5 = ap[5], j6 = ap[6], j7 = ap[7];
        unsigned o0 = (bs + 0 < re) ? (j0 << 3) : dummy_off;
        unsigned o1 = (bs + 1 < re) ? (j1 << 3) : dummy_off;
        unsigned o2 = (bs + 2 < re) ? (j2 << 3) : dummy_off;
        unsigned o3 = (bs + 3 < re) ? (j3 << 3) : dummy_off;
        unsigned o4 = (bs + 4 < re) ? (j4 << 3) : dummy_off;
        unsigned o5 = (bs + 5 < re) ? (j5 << 3) : dummy_off;
        unsigned o6 = (bs + 6 < re) ? (j6 << 3) : dummy_off;
        unsigned o7 = (bs + 7 < re) ? (j7 << 3) : dummy_off;
        GL2(w0, o0) GL2(w1, o1) GL2(w2, o2) GL2(w3, o3)
        GL2(w4, o4) GL2(w5, o5) GL2(w6, o6) GL2(w7, o7)
        asm volatile("s_waitcnt vmcnt(0)" ::: "memory");
        __builtin_amdgcn_sched_barrier(0);
        a0 += w0[0] + w1[0] + w2[0] + w3[0] + w4[0] + w5[0] + w6[0] + w7[0];
        a1 += w0[1] + w1[1] + w2[1] + w3[1] + w4[1] + w5[1] + w6[1] + w7[1];
    }
    const float2* h2p = (const float2*)hs2;
    float2 selfv = h2p[node];
    float dv = dinv[node];
    float2 r;
    r.x = fmaf(dv, a0 + selfv.x, b2[0]);
    r.y = fmaf(dv, a1 + selfv.y, b2[1]);
    out[node] = r;
}

// ---------- launcher ----------
extern "C" void kernel_launch(void* const* d_in, const int* in_sizes, int n_in,
                              void* d_out, int out_size, void* d_ws, size_t ws_size,
                              hipStream_t stream) {
    const float* x   = (const float*)d_in[0];
    const int*   ei  = (const int*)d_in[1];
    const int*   srcv = ei;
    const int*   dstv = ei + N_EDGES;
    const float* W1  = (const float*)d_in[2];
    const float* b1  = (const float*)d_in[3];
    const float* W2  = (const float*)d_in[4];
    const float* b2  = (const float*)d_in[5];
    float* out = (float*)d_out;

    char* w = (char*)d_ws;
    unsigned* adj        = (unsigned*)w;  w += (size_t)(N_EDGES + 8) * 4;  // 12.8 MB + pad (in-place CSR)
    unsigned* blockHist  = (unsigned*)w;  w += (size_t)NB * G * 4;         // 1.25 MB
    unsigned* total      = (unsigned*)w;  w += (size_t)NB * 4;
    unsigned* bucketBase = (unsigned*)w;  w += (size_t)(NB + 1) * 4;
    int*      rowstart   = (int*)w;       w += (size_t)(N_NODES + 1) * 4;  // 0.4 MB
    w = (char*)(((size_t)w + 15) & ~(size_t)15);
    float* dinv  = (float*)w;  w += (size_t)N_NODES * 4;                   // 0.4 MB
    char*  hs    = w;          w += (size_t)NPAD * HIDDEN * 2;             // 3.2 MB fp16
    float* hs2   = (float*)w;                                              // 0.8 MB

    k_hist        <<<G, 256, 0, stream>>>(dstv, blockHist);
    k_scan_blocks <<<NB, 1024, 0, stream>>>(blockHist, total);
    k_scan_buckets<<<1, 512, 0, stream>>>(total, bucketBase, rowstart);
    k_scatter     <<<G, 256, 0, stream>>>(srcv, dstv, blockHist, bucketBase, adj);
    k_sortmm      <<<NB, 512, 0, stream>>>(adj, bucketBase, x, W1, rowstart, dinv, hs);
    k_agg1        <<<(2 * NPAD) / 256, 256, 0, stream>>>(adj, rowstart, hs, dinv,
                                                         b1, W2, (float2*)hs2);
    k_agg2        <<<(NPAD + 255) / 256, 256, 0, stream>>>(adj, rowstart, (const char*)hs2,
                                                           dinv, b2, (float2*)out);
}

// Round 21
// 113.951 us; speedup vs baseline: 1.0327x; 1.0327x over previous
//
#include <hip/hip_runtime.h>

#define N_NODES 100000
#define N_EDGES 3200000
#define F_IN    128
#define HIDDEN  16
#define F_OUT   2

#define BSZ     256                  // nodes per bucket
#define NB      391                  // ceil(N_NODES / BSZ)
#define NPAD    (NB * BSZ)           // 100096 padded node rows
#define G       800                  // edge-partition blocks for hist/scatter
#define EPB     (N_EDGES / G)        // 4000 edges per partition (exact, even)
#define DUMMY_E 100000u              // zeroed pad row used for clamped slots
#define STCAP   8768                 // LDS stage capacity (mean 8192 + 6.4 sigma)

typedef float  f32x4 __attribute__((ext_vector_type(4)));
typedef float  f32x2 __attribute__((ext_vector_type(2)));
typedef _Float16 half8 __attribute__((ext_vector_type(8)));

// ---------- P1: per-partition bucket histogram (r12-proven) ----------
__global__ __launch_bounds__(256) void k_hist(const int* __restrict__ dst,
                                              unsigned* __restrict__ blockHist) {
    __shared__ unsigned h0[NB];
    __shared__ unsigned h1[NB];
    int t = threadIdx.x, g = blockIdx.x;
    for (int i = t; i < NB; i += 256) { h0[i] = 0u; h1[i] = 0u; }
    __syncthreads();
    const int2* d2 = (const int2*)(dst + g * EPB);
    unsigned* myh = (t & 1) ? h1 : h0;
    for (int i = t; i < EPB / 2; i += 256) {
        int2 v = d2[i];
        atomicAdd(&myh[(unsigned)v.x >> 8], 1u);
        atomicAdd(&myh[(unsigned)v.y >> 8], 1u);
    }
    __syncthreads();
    for (int i = t; i < NB; i += 256) blockHist[i * G + g] = h0[i] + h1[i];
}

// ---------- P2: per-bucket exclusive scan over partitions (r12-proven) ----------
__global__ __launch_bounds__(1024) void k_scan_blocks(unsigned* __restrict__ blockHist,
                                                      unsigned* __restrict__ total) {
    __shared__ unsigned s[1024];
    int b = blockIdx.x, t = threadIdx.x;
    unsigned v = (t < G) ? blockHist[b * G + t] : 0u;
    s[t] = v;
    __syncthreads();
    for (int off = 1; off < 1024; off <<= 1) {
        unsigned xv = (t >= off) ? s[t - off] : 0u;
        __syncthreads();
        s[t] += xv;
        __syncthreads();
    }
    if (t < G) blockHist[b * G + t] = s[t] - v;
    if (t == 1023) total[b] = s[t];
}

// ---------- P2c: exclusive scan of bucket totals (r12-proven) ----------
__global__ __launch_bounds__(512) void k_scan_buckets(const unsigned* __restrict__ total,
                                                      unsigned* __restrict__ bucketBase,
                                                      int* __restrict__ rowstart) {
    __shared__ unsigned s[512];
    int t = threadIdx.x;
    unsigned v = (t < NB) ? total[t] : 0u;
    s[t] = v;
    __syncthreads();
    for (int off = 1; off < 512; off <<= 1) {
        unsigned xv = (t >= off) ? s[t - off] : 0u;
        __syncthreads();
        s[t] += xv;
        __syncthreads();
    }
    if (t < NB) bucketBase[t] = s[t] - v;
    if (t == 511) {
        bucketBase[NB] = s[t];                 // == N_EDGES
        rowstart[N_NODES] = (int)s[t];
    }
}

// ---------- P3: LDS counting-sort scatter (r12-proven) ----------
// entry: (dst & 255) << 17 | src ; LDS ~31.3 KB -> 5 blocks/CU
__global__ __launch_bounds__(256) void k_scatter(const int* __restrict__ src,
                                                 const int* __restrict__ dst,
                                                 const unsigned* __restrict__ blockHist,
                                                 const unsigned* __restrict__ bucketBase,
                                                 unsigned* __restrict__ adj) {
    __shared__ unsigned stage[EPB];            // 16.0 KB
    __shared__ unsigned short stage_b[EPB];    // 8.0 KB
    __shared__ unsigned hist[NB];              // cursor
    __shared__ unsigned h1[NB];                // sub-hist
    __shared__ unsigned lstart[NB];
    __shared__ unsigned gbase[NB];
    __shared__ unsigned ssum[256];
    int t = threadIdx.x, g = blockIdx.x;
    for (int i = t; i < NB; i += 256) {
        hist[i] = 0u; h1[i] = 0u;
        gbase[i] = bucketBase[i] + blockHist[i * G + g];
    }
    __syncthreads();
    const int2* s2 = (const int2*)(src + g * EPB);
    const int2* d2 = (const int2*)(dst + g * EPB);
    unsigned* myh = (t & 1) ? h1 : hist;
    for (int i = t; i < EPB / 2; i += 256) {
        int2 v = d2[i];
        atomicAdd(&myh[(unsigned)v.x >> 8], 1u);
        atomicAdd(&myh[(unsigned)v.y >> 8], 1u);
    }
    __syncthreads();
    int i0 = t * 2;
    unsigned v0 = (i0 + 0 < NB) ? hist[i0 + 0] + h1[i0 + 0] : 0u;
    unsigned v1 = (i0 + 1 < NB) ? hist[i0 + 1] + h1[i0 + 1] : 0u;
    unsigned my = v0 + v1;
    ssum[t] = my;
    __syncthreads();
    for (int off = 1; off < 256; off <<= 1) {
        unsigned xv = (t >= off) ? ssum[t - off] : 0u;
        __syncthreads();
        ssum[t] += xv;
        __syncthreads();
    }
    unsigned e0 = ssum[t] - my;
    __syncthreads();
    unsigned e1 = e0 + v0;
    if (i0 + 0 < NB) { lstart[i0 + 0] = e0; hist[i0 + 0] = e0; }
    if (i0 + 1 < NB) { lstart[i0 + 1] = e1; hist[i0 + 1] = e1; }
    __syncthreads();
    for (int i = t; i < EPB / 2; i += 256) {
        int2 sv = s2[i], dv = d2[i];
        unsigned bkt0 = (unsigned)dv.x >> 8;
        unsigned pos0 = atomicAdd(&hist[bkt0], 1u);
        stage[pos0] = ((unsigned)(dv.x & 255) << 17) | (unsigned)sv.x;
        stage_b[pos0] = (unsigned short)bkt0;
        unsigned bkt1 = (unsigned)dv.y >> 8;
        unsigned pos1 = atomicAdd(&hist[bkt1], 1u);
        stage[pos1] = ((unsigned)(dv.y & 255) << 17) | (unsigned)sv.y;
        stage_b[pos1] = (unsigned short)bkt1;
    }
    __syncthreads();
    for (int j = t; j < EPB; j += 256) {
        unsigned bkt = stage_b[j];
        adj[gbase[bkt] + (j - lstart[bkt])] = stage[j];
    }
}

// ---------- P4: in-bucket counting sort -> CSR + FUSED mm1 (r19-proven) ----------
// 4-way privatized hist/cursor (wave-pair) + LDS-staged sorted bucket
// with coalesced adj2 writes. mm phase = register version.
__global__ __launch_bounds__(512) void k_sortmm(const unsigned* __restrict__ adj,
                                                const unsigned* __restrict__ bucketBase,
                                                const float* __restrict__ x,
                                                const float* __restrict__ W1,
                                                unsigned* __restrict__ adj2,
                                                int* __restrict__ rowstart,
                                                float* __restrict__ dinv,
                                                char* __restrict__ hs) {
    __shared__ float sW[F_IN * HIDDEN];        // 8 KB
    __shared__ unsigned stage[STCAP];          // 34.25 KB sorted bucket
    __shared__ unsigned hist4[4][BSZ];         // 4 KB privatized hist
    __shared__ unsigned cur4[4][BSZ];          // 4 KB privatized cursors
    __shared__ unsigned sc[BSZ];               // 1 KB scan
    __shared__ float sdinv[BSZ];               // 1 KB
    int b = blockIdx.x, t = threadIdx.x;
    int sub = t >> 7;                           // wave-pair id 0..3
    for (int i = t; i < F_IN * HIDDEN; i += 512) sW[i] = W1[i];
    for (int i = t; i < 4 * BSZ; i += 512) ((unsigned*)hist4)[i] = 0u;
    __syncthreads();
    int e0 = (int)bucketBase[b], e1 = (int)bucketBase[b + 1];
    // phase 1: privatized histogram (contention only within wave-pair)
    for (int i = e0 + t; i < e1; i += 512) atomicAdd(&hist4[sub][adj[i] >> 17], 1u);
    __syncthreads();
    unsigned d0 = 0, d1 = 0, d2 = 0, d3 = 0, deg = 0;
    if (t < BSZ) {
        d0 = hist4[0][t]; d1 = hist4[1][t]; d2 = hist4[2][t]; d3 = hist4[3][t];
        deg = d0 + d1 + d2 + d3;
        sc[t] = deg;
    }
    __syncthreads();
    for (int off = 1; off < BSZ; off <<= 1) {
        unsigned a = 0;
        if (t < BSZ && t >= off) a = sc[t - off];
        __syncthreads();
        if (t < BSZ) sc[t] += a;
        __syncthreads();
    }
    if (t < BSZ) {
        unsigned excl = sc[t] - deg;
        cur4[0][t] = excl;
        cur4[1][t] = excl + d0;
        cur4[2][t] = excl + d0 + d1;
        cur4[3][t] = excl + d0 + d1 + d2;
        float dv = rsqrtf((float)(deg + 1u));
        sdinv[t] = dv;
        int node = b * BSZ + t;
        if (node < N_NODES) {
            rowstart[node] = e0 + (int)excl;
            dinv[node] = dv;
        }
    }
    __syncthreads();
    // phase 2: CSR scatter into LDS stage (relative positions)
    for (int i = e0 + t; i < e1; i += 512) {
        unsigned v = adj[i];
        unsigned pos = atomicAdd(&cur4[sub][v >> 17], 1u);
        stage[pos] = v & 0x1FFFFu;
    }
    __syncthreads();
    // phase 3: coalesced adj2 write
    int len = e1 - e0;
    for (int j = t; j < len; j += 512) adj2[e0 + j] = stage[j];
    // phase 4: fused mm1 (register version): 2 lanes/node, 64 f-values each
    int nl = t >> 1, half = t & 1;
    int node = b * BSZ + nl;
    if (node >= N_NODES) {                     // zero pad rows incl. DUMMY row
        half8 hz = {(_Float16)0.f, (_Float16)0.f, (_Float16)0.f, (_Float16)0.f,
                    (_Float16)0.f, (_Float16)0.f, (_Float16)0.f, (_Float16)0.f};
        if (node < NPAD) *(half8*)(hs + (size_t)node * 32 + half * 16) = hz;
        return;
    }
    const f32x4* xr = (const f32x4*)(x + (size_t)node * F_IN + half * 64);
    const f32x4* wv = (const f32x4*)sW;
    f32x4 a0 = {0.f,0.f,0.f,0.f}, a1 = a0, a2 = a0, a3 = a0;
    #pragma unroll 4
    for (int k = 0; k < 16; ++k) {
        f32x4 xq = xr[k];
        int f0 = (half << 6) + (k << 2);
        #pragma unroll
        for (int j = 0; j < 4; ++j) {
            float xv = xq[j];
            const f32x4* wr = wv + (size_t)(f0 + j) * 4;
            a0 += xv * wr[0];
            a1 += xv * wr[1];
            a2 += xv * wr[2];
            a3 += xv * wr[3];
        }
    }
    a0[0] += __shfl_xor(a0[0], 1); a0[1] += __shfl_xor(a0[1], 1);
    a0[2] += __shfl_xor(a0[2], 1); a0[3] += __shfl_xor(a0[3], 1);
    a1[0] += __shfl_xor(a1[0], 1); a1[1] += __shfl_xor(a1[1], 1);
    a1[2] += __shfl_xor(a1[2], 1); a1[3] += __shfl_xor(a1[3], 1);
    a2[0] += __shfl_xor(a2[0], 1); a2[1] += __shfl_xor(a2[1], 1);
    a2[2] += __shfl_xor(a2[2], 1); a2[3] += __shfl_xor(a2[3], 1);
    a3[0] += __shfl_xor(a3[0], 1); a3[1] += __shfl_xor(a3[1], 1);
    a3[2] += __shfl_xor(a3[2], 1); a3[3] += __shfl_xor(a3[3], 1);
    float dv = sdinv[nl];
    f32x4 u = half ? a2 : a0;
    f32x4 v2 = half ? a3 : a1;
    half8 hh;
    hh[0] = (_Float16)(u[0] * dv);  hh[1] = (_Float16)(u[1] * dv);
    hh[2] = (_Float16)(u[2] * dv);  hh[3] = (_Float16)(u[3] * dv);
    hh[4] = (_Float16)(v2[0] * dv); hh[5] = (_Float16)(v2[1] * dv);
    hh[6] = (_Float16)(v2[2] * dv); hh[7] = (_Float16)(v2[3] * dv);
    *(half8*)(hs + (size_t)node * 32 + half * 16) = hh;
}

// ---------- layer-1 aggregation + FUSED layer-2 matmul (r12-proven) ----------
__global__ __launch_bounds__(256) void k_agg1(const unsigned* __restrict__ adj2,
                                              const int* __restrict__ rowstart,
                                              const char* __restrict__ hs,
                                              const float* __restrict__ dinv,
                                              const float* __restrict__ b1,
                                              const float* __restrict__ W2,
                                              float2* __restrict__ hs2) {
    int g = blockIdx.x * 256 + threadIdx.x;
    int node = g >> 1, le = g & 1;
    if (node >= N_NODES) {                     // zero pad rows incl. DUMMY
        if (le == 0 && node < NPAD) { float2 z = {0.f, 0.f}; hs2[node] = z; }
        return;
    }
    int rs = rowstart[node], re = rowstart[node + 1];
    unsigned le16 = (unsigned)le * 16u;
    unsigned dummy_off = DUMMY_E * 32u + le16;

    float a0 = 0.f, a1 = 0.f, a2 = 0.f, a3 = 0.f, a4 = 0.f, a5 = 0.f, a6 = 0.f, a7 = 0.f;
    f32x4 w0, w1, w2, w3, w4, w5, w6, w7;

#define GL1(dst, o) asm volatile("global_load_dwordx4 %0, %1, %2" \
    : "=v"(dst) : "v"(o), "s"(hs) : "memory");
#define AC1(w_) { half8 h8; __builtin_memcpy(&h8, &w_, 16); \
    a0 += (float)h8[0]; a1 += (float)h8[1]; a2 += (float)h8[2]; a3 += (float)h8[3]; \
    a4 += (float)h8[4]; a5 += (float)h8[5]; a6 += (float)h8[6]; a7 += (float)h8[7]; }

    for (int bs = rs; bs < re; bs += 8) {
        const unsigned* ap = adj2 + bs;        // adj2 padded by 8 -> safe reads
        unsigned j0 = ap[0], j1 = ap[1], j2 = ap[2], j3 = ap[3];
        unsigned j4 = ap[4], j5 = ap[5], j6 = ap[6], j7 = ap[7];
        unsigned o0 = (bs + 0 < re) ? (j0 << 5) + le16 : dummy_off;
        unsigned o1 = (bs + 1 < re) ? (j1 << 5) + le16 : dummy_off;
        unsigned o2 = (bs + 2 < re) ? (j2 << 5) + le16 : dummy_off;
        unsigned o3 = (bs + 3 < re) ? (j3 << 5) + le16 : dummy_off;
        unsigned o4 = (bs + 4 < re) ? (j4 << 5) + le16 : dummy_off;
        unsigned o5 = (bs + 5 < re) ? (j5 << 5) + le16 : dummy_off;
        unsigned o6 = (bs + 6 < re) ? (j6 << 5) + le16 : dummy_off;
        unsigned o7 = (bs + 7 < re) ? (j7 << 5) + le16 : dummy_off;
        GL1(w0, o0) GL1(w1, o1) GL1(w2, o2) GL1(w3, o3)
        GL1(w4, o4) GL1(w5, o5) GL1(w6, o6) GL1(w7, o7)
        asm volatile("s_waitcnt vmcnt(0)" ::: "memory");
        __builtin_amdgcn_sched_barrier(0);
        AC1(w0) AC1(w1) AC1(w2) AC1(w3) AC1(w4) AC1(w5) AC1(w6) AC1(w7)
    }
    const _Float16* selfrow = (const _Float16*)(hs + (size_t)node * 32 + le16);
    float dv = dinv[node];
    float q0 = dv * (a0 + (float)selfrow[0]), q1 = dv * (a1 + (float)selfrow[1]);
    float q2 = dv * (a2 + (float)selfrow[2]), q3 = dv * (a3 + (float)selfrow[3]);
    float q4 = dv * (a4 + (float)selfrow[4]), q5 = dv * (a5 + (float)selfrow[5]);
    float q6 = dv * (a6 + (float)selfrow[6]), q7 = dv * (a7 + (float)selfrow[7]);
    const float4* b1v = (const float4*)(b1 + le * 8);
    float4 ba = b1v[0], bb = b1v[1];
    const float4* w2v = (const float4*)(W2 + le * 16);
    float4 wA = w2v[0], wB = w2v[1], wC = w2v[2], wD = w2v[3];
    float p0 = 0.f, p1 = 0.f, r;
    r = fmaxf(q0 + ba.x, 0.f); p0 = fmaf(r, wA.x, p0); p1 = fmaf(r, wA.y, p1);
    r = fmaxf(q1 + ba.y, 0.f); p0 = fmaf(r, wA.z, p0); p1 = fmaf(r, wA.w, p1);
    r = fmaxf(q2 + ba.z, 0.f); p0 = fmaf(r, wB.x, p0); p1 = fmaf(r, wB.y, p1);
    r = fmaxf(q3 + ba.w, 0.f); p0 = fmaf(r, wB.z, p0); p1 = fmaf(r, wB.w, p1);
    r = fmaxf(q4 + bb.x, 0.f); p0 = fmaf(r, wC.x, p0); p1 = fmaf(r, wC.y, p1);
    r = fmaxf(q5 + bb.y, 0.f); p0 = fmaf(r, wC.z, p0); p1 = fmaf(r, wC.w, p1);
    r = fmaxf(q6 + bb.z, 0.f); p0 = fmaf(r, wD.x, p0); p1 = fmaf(r, wD.y, p1);
    r = fmaxf(q7 + bb.w, 0.f); p0 = fmaf(r, wD.z, p0); p1 = fmaf(r, wD.w, p1);
    p0 += __shfl_xor(p0, 1);
    p1 += __shfl_xor(p1, 1);
    if (le == 0) {
        float2 h2; h2.x = p0 * dv; h2.y = p1 * dv;
        hs2[node] = h2;
    }
}

// ---------- layer-2 aggregation + finalize (r12-proven) ----------
__global__ __launch_bounds__(256) void k_agg2(const unsigned* __restrict__ adj2,
                                              const int* __restrict__ rowstart,
                                              const char* __restrict__ hs2,
                                              const float* __restrict__ dinv,
                                              const float* __restrict__ b2,
                                              float2* __restrict__ out) {
    int node = blockIdx.x * 256 + threadIdx.x;
    if (node >= N_NODES) return;
    int rs = rowstart[node], re = rowstart[node + 1];
    unsigned dummy_off = DUMMY_E * 8u;

    float a0 = 0.f, a1 = 0.f;
    f32x2 w0, w1, w2, w3, w4, w5, w6, w7;

#define GL2(dst, o) asm volatile("global_load_dwordx2 %0, %1, %2" \
    : "=v"(dst) : "v"(o), "s"(hs2) : "memory");

    for (int bs = rs; bs < re; bs += 8) {
        const unsigned* ap = adj2 + bs;
        unsigned j0 = ap[0], j1 = ap[1], j2 = ap[2], j3 = ap[3];
        unsigned j4 = ap[4], j5 = ap[5], j6 = ap[6], j7 = ap[7];
        unsigned o0 = (bs + 0 < re) ? (j0 << 3) : dummy_off;
        unsigned o1 = (bs + 1 < re) ? (j1 << 3) : dummy_off;
        unsigned o2 = (bs + 2 < re) ? (j2 << 3) : dummy_off;
        unsigned o3 = (bs + 3 < re) ? (j3 << 3) : dummy_off;
        unsigned o4 = (bs + 4 < re) ? (j4 << 3) : dummy_off;
        unsigned o5 = (bs + 5 < re) ? (j5 << 3) : dummy_off;
        unsigned o6 = (bs + 6 < re) ? (j6 << 3) : dummy_off;
        unsigned o7 = (bs + 7 < re) ? (j7 << 3) : dummy_off;
        GL2(w0, o0) GL2(w1, o1) GL2(w2, o2) GL2(w3, o3)
        GL2(w4, o4) GL2(w5, o5) GL2(w6, o6) GL2(w7, o7)
        asm volatile("s_waitcnt vmcnt(0)" ::: "memory");
        __builtin_amdgcn_sched_barrier(0);
        a0 += w0[0] + w1[0] + w2[0] + w3[0] + w4[0] + w5[0] + w6[0] + w7[0];
        a1 += w0[1] + w1[1] + w2[1] + w3[1] + w4[1] + w5[1] + w6[1] + w7[1];
    }
    const float2* h2p = (const float2*)hs2;
    float2 selfv = h2p[node];
    float dv = dinv[node];
    float2 r;
    r.x = fmaf(dv, a0 + selfv.x, b2[0]);
    r.y = fmaf(dv, a1 + selfv.y, b2[1]);
    out[node] = r;
}

// ---------- launcher ----------
extern "C" void kernel_launch(void* const* d_in, const int* in_sizes, int n_in,
                              void* d_out, int out_size, void* d_ws, size_t ws_size,
                              hipStream_t stream) {
    const float* x   = (const float*)d_in[0];
    const int*   ei  = (const int*)d_in[1];
    const int*   srcv = ei;
    const int*   dstv = ei + N_EDGES;
    const float* W1  = (const float*)d_in[2];
    const float* b1  = (const float*)d_in[3];
    const float* W2  = (const float*)d_in[4];
    const float* b2  = (const float*)d_in[5];
    float* out = (float*)d_out;

    char* w = (char*)d_ws;
    unsigned* adj        = (unsigned*)w;  w += (size_t)N_EDGES * 4;        // 12.8 MB
    unsigned* adj2       = (unsigned*)w;  w += (size_t)(N_EDGES + 8) * 4;  // 12.8 MB + pad
    unsigned* blockHist  = (unsigned*)w;  w += (size_t)NB * G * 4;         // 1.25 MB
    unsigned* total      = (unsigned*)w;  w += (size_t)NB * 4;
    unsigned* bucketBase = (unsigned*)w;  w += (size_t)(NB + 1) * 4;
    int*      rowstart   = (int*)w;       w += (size_t)(N_NODES + 1) * 4;  // 0.4 MB
    w = (char*)(((size_t)w + 15) & ~(size_t)15);
    float* dinv  = (float*)w;  w += (size_t)N_NODES * 4;                   // 0.4 MB
    char*  hs    = w;          w += (size_t)NPAD * HIDDEN * 2;             // 3.2 MB fp16
    float* hs2   = (float*)w;                                              // 0.8 MB

    k_hist        <<<G, 256, 0, stream>>>(dstv, blockHist);
    k_scan_blocks <<<NB, 1024, 0, stream>>>(blockHist, total);
    k_scan_buckets<<<1, 512, 0, stream>>>(total, bucketBase, rowstart);
    k_scatter     <<<G, 256, 0, stream>>>(srcv, dstv, blockHist, bucketBase, adj);
    k_sortmm      <<<NB, 512, 0, stream>>>(adj, bucketBase, x, W1, adj2, rowstart, dinv, hs);
    k_agg1        <<<(2 * NPAD) / 256, 256, 0, stream>>>(adj2, rowstart, hs, dinv,
                                                         b1, W2, (float2*)hs2);
    k_agg2        <<<(NPAD + 255) / 256, 256, 0, stream>>>(adj2, rowstart, (const char*)hs2,
                                                           dinv, b2, (float2*)out);
}

// Round 22
// 113.297 us; speedup vs baseline: 1.0386x; 1.0058x over previous
//
#include <hip/hip_runtime.h>

#define N_NODES 100000
#define N_EDGES 3200000
#define F_IN    128
#define HIDDEN  16
#define F_OUT   2

#define BSZ     256                  // nodes per bucket
#define NB      391                  // ceil(N_NODES / BSZ)
#define NPAD    (NB * BSZ)           // 100096 padded node rows
#define G       800                  // edge-partition blocks for hist/scatter
#define EPB     (N_EDGES / G)        // 4000 edges per partition (exact, even)
#define DUMMY_E 100000u              // zeroed pad row used for clamped slots
#define STCAP   8768                 // LDS stage capacity (mean 8192 + 6.4 sigma)

typedef float  f32x4 __attribute__((ext_vector_type(4)));
typedef float  f32x2 __attribute__((ext_vector_type(2)));
typedef _Float16 half8 __attribute__((ext_vector_type(8)));

// ---------- P1: per-partition bucket histogram (r12-proven) ----------
__global__ __launch_bounds__(256) void k_hist(const int* __restrict__ dst,
                                              unsigned* __restrict__ blockHist) {
    __shared__ unsigned h0[NB];
    __shared__ unsigned h1[NB];
    int t = threadIdx.x, g = blockIdx.x;
    for (int i = t; i < NB; i += 256) { h0[i] = 0u; h1[i] = 0u; }
    __syncthreads();
    const int2* d2 = (const int2*)(dst + g * EPB);
    unsigned* myh = (t & 1) ? h1 : h0;
    for (int i = t; i < EPB / 2; i += 256) {
        int2 v = d2[i];
        atomicAdd(&myh[(unsigned)v.x >> 8], 1u);
        atomicAdd(&myh[(unsigned)v.y >> 8], 1u);
    }
    __syncthreads();
    for (int i = t; i < NB; i += 256) blockHist[i * G + g] = h0[i] + h1[i];
}

// ---------- P2: per-bucket exclusive scan over partitions (r12-proven) ----------
__global__ __launch_bounds__(1024) void k_scan_blocks(unsigned* __restrict__ blockHist,
                                                      unsigned* __restrict__ total) {
    __shared__ unsigned s[1024];
    int b = blockIdx.x, t = threadIdx.x;
    unsigned v = (t < G) ? blockHist[b * G + t] : 0u;
    s[t] = v;
    __syncthreads();
    for (int off = 1; off < 1024; off <<= 1) {
        unsigned xv = (t >= off) ? s[t - off] : 0u;
        __syncthreads();
        s[t] += xv;
        __syncthreads();
    }
    if (t < G) blockHist[b * G + t] = s[t] - v;
    if (t == 1023) total[b] = s[t];
}

// ---------- P2c: exclusive scan of bucket totals (r12-proven) ----------
__global__ __launch_bounds__(512) void k_scan_buckets(const unsigned* __restrict__ total,
                                                      unsigned* __restrict__ bucketBase,
                                                      int* __restrict__ rowstart) {
    __shared__ unsigned s[512];
    int t = threadIdx.x;
    unsigned v = (t < NB) ? total[t] : 0u;
    s[t] = v;
    __syncthreads();
    for (int off = 1; off < 512; off <<= 1) {
        unsigned xv = (t >= off) ? s[t - off] : 0u;
        __syncthreads();
        s[t] += xv;
        __syncthreads();
    }
    if (t < NB) bucketBase[t] = s[t] - v;
    if (t == 511) {
        bucketBase[NB] = s[t];                 // == N_EDGES
        rowstart[N_NODES] = (int)s[t];
    }
}

// ---------- P3: LDS counting-sort scatter (r12-proven) ----------
// entry: (dst & 255) << 17 | src ; LDS ~31.3 KB -> 5 blocks/CU
__global__ __launch_bounds__(256) void k_scatter(const int* __restrict__ src,
                                                 const int* __restrict__ dst,
                                                 const unsigned* __restrict__ blockHist,
                                                 const unsigned* __restrict__ bucketBase,
                                                 unsigned* __restrict__ adj) {
    __shared__ unsigned stage[EPB];            // 16.0 KB
    __shared__ unsigned short stage_b[EPB];    // 8.0 KB
    __shared__ unsigned hist[NB];              // cursor
    __shared__ unsigned h1[NB];                // sub-hist
    __shared__ unsigned lstart[NB];
    __shared__ unsigned gbase[NB];
    __shared__ unsigned ssum[256];
    int t = threadIdx.x, g = blockIdx.x;
    for (int i = t; i < NB; i += 256) {
        hist[i] = 0u; h1[i] = 0u;
        gbase[i] = bucketBase[i] + blockHist[i * G + g];
    }
    __syncthreads();
    const int2* s2 = (const int2*)(src + g * EPB);
    const int2* d2 = (const int2*)(dst + g * EPB);
    unsigned* myh = (t & 1) ? h1 : hist;
    for (int i = t; i < EPB / 2; i += 256) {
        int2 v = d2[i];
        atomicAdd(&myh[(unsigned)v.x >> 8], 1u);
        atomicAdd(&myh[(unsigned)v.y >> 8], 1u);
    }
    __syncthreads();
    int i0 = t * 2;
    unsigned v0 = (i0 + 0 < NB) ? hist[i0 + 0] + h1[i0 + 0] : 0u;
    unsigned v1 = (i0 + 1 < NB) ? hist[i0 + 1] + h1[i0 + 1] : 0u;
    unsigned my = v0 + v1;
    ssum[t] = my;
    __syncthreads();
    for (int off = 1; off < 256; off <<= 1) {
        unsigned xv = (t >= off) ? ssum[t - off] : 0u;
        __syncthreads();
        ssum[t] += xv;
        __syncthreads();
    }
    unsigned e0 = ssum[t] - my;
    __syncthreads();
    unsigned e1 = e0 + v0;
    if (i0 + 0 < NB) { lstart[i0 + 0] = e0; hist[i0 + 0] = e0; }
    if (i0 + 1 < NB) { lstart[i0 + 1] = e1; hist[i0 + 1] = e1; }
    __syncthreads();
    for (int i = t; i < EPB / 2; i += 256) {
        int2 sv = s2[i], dv = d2[i];
        unsigned bkt0 = (unsigned)dv.x >> 8;
        unsigned pos0 = atomicAdd(&hist[bkt0], 1u);
        stage[pos0] = ((unsigned)(dv.x & 255) << 17) | (unsigned)sv.x;
        stage_b[pos0] = (unsigned short)bkt0;
        unsigned bkt1 = (unsigned)dv.y >> 8;
        unsigned pos1 = atomicAdd(&hist[bkt1], 1u);
        stage[pos1] = ((unsigned)(dv.y & 255) << 17) | (unsigned)sv.y;
        stage_b[pos1] = (unsigned short)bkt1;
    }
    __syncthreads();
    for (int j = t; j < EPB; j += 256) {
        unsigned bkt = stage_b[j];
        adj[gbase[bkt] + (j - lstart[bkt])] = stage[j];
    }
}

// ---------- P4: in-bucket counting sort -> CSR + FUSED mm1 ----------
// Single global read (bucket -> LDS + privatized histogram), inverse
// permutation in LDS, COALESCED adj2 write (stage[ipos[j]]), fused mm1.
__global__ __launch_bounds__(512) void k_sortmm(const unsigned* __restrict__ adj,
                                                const unsigned* __restrict__ bucketBase,
                                                const float* __restrict__ x,
                                                const float* __restrict__ W1,
                                                unsigned* __restrict__ adj2,
                                                int* __restrict__ rowstart,
                                                float* __restrict__ dinv,
                                                char* __restrict__ hs) {
    __shared__ float sW[F_IN * HIDDEN];        // 8 KB
    __shared__ unsigned stage[STCAP];          // 34.25 KB raw bucket entries
    __shared__ unsigned short ipos[STCAP];     // 17.1 KB inverse permutation
    __shared__ unsigned hist4[4][BSZ];         // 4 KB privatized hist
    __shared__ unsigned cur4[4][BSZ];          // 4 KB privatized cursors
    __shared__ unsigned sc[BSZ];               // 1 KB scan
    __shared__ float sdinv[BSZ];               // 1 KB
    int b = blockIdx.x, t = threadIdx.x;
    int sub = t >> 7;                           // wave-pair id 0..3
    for (int i = t; i < F_IN * HIDDEN; i += 512) sW[i] = W1[i];
    for (int i = t; i < 4 * BSZ; i += 512) ((unsigned*)hist4)[i] = 0u;
    __syncthreads();
    int e0 = (int)bucketBase[b], e1 = (int)bucketBase[b + 1];
    int len = e1 - e0;
    // phase 1: single coalesced global read -> LDS + privatized histogram
    for (int i = t; i < len; i += 512) {
        unsigned v = adj[e0 + i];
        stage[i] = v;
        atomicAdd(&hist4[sub][v >> 17], 1u);
    }
    __syncthreads();
    unsigned d0 = 0, d1 = 0, d2 = 0, d3 = 0, deg = 0;
    if (t < BSZ) {
        d0 = hist4[0][t]; d1 = hist4[1][t]; d2 = hist4[2][t]; d3 = hist4[3][t];
        deg = d0 + d1 + d2 + d3;
        sc[t] = deg;
    }
    __syncthreads();
    for (int off = 1; off < BSZ; off <<= 1) {
        unsigned a = 0;
        if (t < BSZ && t >= off) a = sc[t - off];
        __syncthreads();
        if (t < BSZ) sc[t] += a;
        __syncthreads();
    }
    if (t < BSZ) {
        unsigned excl = sc[t] - deg;
        cur4[0][t] = excl;
        cur4[1][t] = excl + d0;
        cur4[2][t] = excl + d0 + d1;
        cur4[3][t] = excl + d0 + d1 + d2;
        float dv = rsqrtf((float)(deg + 1u));
        sdinv[t] = dv;
        int node = b * BSZ + t;
        if (node < N_NODES) {
            rowstart[node] = e0 + (int)excl;
            dinv[node] = dv;
        }
    }
    __syncthreads();
    // phase 2: build inverse permutation in LDS (scattered LDS writes, cheap)
    for (int i = t; i < len; i += 512) {
        unsigned pos = atomicAdd(&cur4[sub][stage[i] >> 17], 1u);
        ipos[pos] = (unsigned short)i;
    }
    __syncthreads();
    // phase 3: coalesced adj2 write via inverse permutation
    for (int j = t; j < len; j += 512)
        adj2[e0 + j] = stage[ipos[j]] & 0x1FFFFu;
    // phase 4: fused mm1 (register version): 2 lanes/node, 64 f-values each
    int nl = t >> 1, half = t & 1;
    int node = b * BSZ + nl;
    if (node >= N_NODES) {                     // zero pad rows incl. DUMMY row
        half8 hz = {(_Float16)0.f, (_Float16)0.f, (_Float16)0.f, (_Float16)0.f,
                    (_Float16)0.f, (_Float16)0.f, (_Float16)0.f, (_Float16)0.f};
        if (node < NPAD) *(half8*)(hs + (size_t)node * 32 + half * 16) = hz;
        return;
    }
    const f32x4* xr = (const f32x4*)(x + (size_t)node * F_IN + half * 64);
    const f32x4* wv = (const f32x4*)sW;
    f32x4 a0 = {0.f,0.f,0.f,0.f}, a1 = a0, a2 = a0, a3 = a0;
    #pragma unroll 4
    for (int k = 0; k < 16; ++k) {
        f32x4 xq = xr[k];
        int f0 = (half << 6) + (k << 2);
        #pragma unroll
        for (int j = 0; j < 4; ++j) {
            float xv = xq[j];
            const f32x4* wr = wv + (size_t)(f0 + j) * 4;
            a0 += xv * wr[0];
            a1 += xv * wr[1];
            a2 += xv * wr[2];
            a3 += xv * wr[3];
        }
    }
    a0[0] += __shfl_xor(a0[0], 1); a0[1] += __shfl_xor(a0[1], 1);
    a0[2] += __shfl_xor(a0[2], 1); a0[3] += __shfl_xor(a0[3], 1);
    a1[0] += __shfl_xor(a1[0], 1); a1[1] += __shfl_xor(a1[1], 1);
    a1[2] += __shfl_xor(a1[2], 1); a1[3] += __shfl_xor(a1[3], 1);
    a2[0] += __shfl_xor(a2[0], 1); a2[1] += __shfl_xor(a2[1], 1);
    a2[2] += __shfl_xor(a2[2], 1); a2[3] += __shfl_xor(a2[3], 1);
    a3[0] += __shfl_xor(a3[0], 1); a3[1] += __shfl_xor(a3[1], 1);
    a3[2] += __shfl_xor(a3[2], 1); a3[3] += __shfl_xor(a3[3], 1);
    float dv = sdinv[nl];
    f32x4 u = half ? a2 : a0;
    f32x4 v2 = half ? a3 : a1;
    half8 hh;
    hh[0] = (_Float16)(u[0] * dv);  hh[1] = (_Float16)(u[1] * dv);
    hh[2] = (_Float16)(u[2] * dv);  hh[3] = (_Float16)(u[3] * dv);
    hh[4] = (_Float16)(v2[0] * dv); hh[5] = (_Float16)(v2[1] * dv);
    hh[6] = (_Float16)(v2[2] * dv); hh[7] = (_Float16)(v2[3] * dv);
    *(half8*)(hs + (size_t)node * 32 + half * 16) = hh;
}

// ---------- layer-1 aggregation + FUSED layer-2 matmul (r12-proven) ----------
__global__ __launch_bounds__(256) void k_agg1(const unsigned* __restrict__ adj2,
                                              const int* __restrict__ rowstart,
                                              const char* __restrict__ hs,
                                              const float* __restrict__ dinv,
                                              const float* __restrict__ b1,
                                              const float* __restrict__ W2,
                                              float2* __restrict__ hs2) {
    int g = blockIdx.x * 256 + threadIdx.x;
    int node = g >> 1, le = g & 1;
    if (node >= N_NODES) {                     // zero pad rows incl. DUMMY
        if (le == 0 && node < NPAD) { float2 z = {0.f, 0.f}; hs2[node] = z; }
        return;
    }
    int rs = rowstart[node], re = rowstart[node + 1];
    unsigned le16 = (unsigned)le * 16u;
    unsigned dummy_off = DUMMY_E * 32u + le16;

    float a0 = 0.f, a1 = 0.f, a2 = 0.f, a3 = 0.f, a4 = 0.f, a5 = 0.f, a6 = 0.f, a7 = 0.f;
    f32x4 w0, w1, w2, w3, w4, w5, w6, w7;

#define GL1(dst, o) asm volatile("global_load_dwordx4 %0, %1, %2" \
    : "=v"(dst) : "v"(o), "s"(hs) : "memory");
#define AC1(w_) { half8 h8; __builtin_memcpy(&h8, &w_, 16); \
    a0 += (float)h8[0]; a1 += (float)h8[1]; a2 += (float)h8[2]; a3 += (float)h8[3]; \
    a4 += (float)h8[4]; a5 += (float)h8[5]; a6 += (float)h8[6]; a7 += (float)h8[7]; }

    for (int bs = rs; bs < re; bs += 8) {
        const unsigned* ap = adj2 + bs;        // adj2 padded by 8 -> safe reads
        unsigned j0 = ap[0], j1 = ap[1], j2 = ap[2], j3 = ap[3];
        unsigned j4 = ap[4], j5 = ap[5], j6 = ap[6], j7 = ap[7];
        unsigned o0 = (bs + 0 < re) ? (j0 << 5) + le16 : dummy_off;
        unsigned o1 = (bs + 1 < re) ? (j1 << 5) + le16 : dummy_off;
        unsigned o2 = (bs + 2 < re) ? (j2 << 5) + le16 : dummy_off;
        unsigned o3 = (bs + 3 < re) ? (j3 << 5) + le16 : dummy_off;
        unsigned o4 = (bs + 4 < re) ? (j4 << 5) + le16 : dummy_off;
        unsigned o5 = (bs + 5 < re) ? (j5 << 5) + le16 : dummy_off;
        unsigned o6 = (bs + 6 < re) ? (j6 << 5) + le16 : dummy_off;
        unsigned o7 = (bs + 7 < re) ? (j7 << 5) + le16 : dummy_off;
        GL1(w0, o0) GL1(w1, o1) GL1(w2, o2) GL1(w3, o3)
        GL1(w4, o4) GL1(w5, o5) GL1(w6, o6) GL1(w7, o7)
        asm volatile("s_waitcnt vmcnt(0)" ::: "memory");
        __builtin_amdgcn_sched_barrier(0);
        AC1(w0) AC1(w1) AC1(w2) AC1(w3) AC1(w4) AC1(w5) AC1(w6) AC1(w7)
    }
    const _Float16* selfrow = (const _Float16*)(hs + (size_t)node * 32 + le16);
    float dv = dinv[node];
    float q0 = dv * (a0 + (float)selfrow[0]), q1 = dv * (a1 + (float)selfrow[1]);
    float q2 = dv * (a2 + (float)selfrow[2]), q3 = dv * (a3 + (float)selfrow[3]);
    float q4 = dv * (a4 + (float)selfrow[4]), q5 = dv * (a5 + (float)selfrow[5]);
    float q6 = dv * (a6 + (float)selfrow[6]), q7 = dv * (a7 + (float)selfrow[7]);
    const float4* b1v = (const float4*)(b1 + le * 8);
    float4 ba = b1v[0], bb = b1v[1];
    const float4* w2v = (const float4*)(W2 + le * 16);
    float4 wA = w2v[0], wB = w2v[1], wC = w2v[2], wD = w2v[3];
    float p0 = 0.f, p1 = 0.f, r;
    r = fmaxf(q0 + ba.x, 0.f); p0 = fmaf(r, wA.x, p0); p1 = fmaf(r, wA.y, p1);
    r = fmaxf(q1 + ba.y, 0.f); p0 = fmaf(r, wA.z, p0); p1 = fmaf(r, wA.w, p1);
    r = fmaxf(q2 + ba.z, 0.f); p0 = fmaf(r, wB.x, p0); p1 = fmaf(r, wB.y, p1);
    r = fmaxf(q3 + ba.w, 0.f); p0 = fmaf(r, wB.z, p0); p1 = fmaf(r, wB.w, p1);
    r = fmaxf(q4 + bb.x, 0.f); p0 = fmaf(r, wC.x, p0); p1 = fmaf(r, wC.y, p1);
    r = fmaxf(q5 + bb.y, 0.f); p0 = fmaf(r, wC.z, p0); p1 = fmaf(r, wC.w, p1);
    r = fmaxf(q6 + bb.z, 0.f); p0 = fmaf(r, wD.x, p0); p1 = fmaf(r, wD.y, p1);
    r = fmaxf(q7 + bb.w, 0.f); p0 = fmaf(r, wD.z, p0); p1 = fmaf(r, wD.w, p1);
    p0 += __shfl_xor(p0, 1);
    p1 += __shfl_xor(p1, 1);
    if (le == 0) {
        float2 h2; h2.x = p0 * dv; h2.y = p1 * dv;
        hs2[node] = h2;
    }
}

// ---------- layer-2 aggregation + finalize (r12-proven) ----------
__global__ __launch_bounds__(256) void k_agg2(const unsigned* __restrict__ adj2,
                                              const int* __restrict__ rowstart,
                                              const char* __restrict__ hs2,
                                              const float* __restrict__ dinv,
                                              const float* __restrict__ b2,
                                              float2* __restrict__ out) {
    int node = blockIdx.x * 256 + threadIdx.x;
    if (node >= N_NODES) return;
    int rs = rowstart[node], re = rowstart[node + 1];
    unsigned dummy_off = DUMMY_E * 8u;

    float a0 = 0.f, a1 = 0.f;
    f32x2 w0, w1, w2, w3, w4, w5, w6, w7;

#define GL2(dst, o) asm volatile("global_load_dwordx2 %0, %1, %2" \
    : "=v"(dst) : "v"(o), "s"(hs2) : "memory");

    for (int bs = rs; bs < re; bs += 8) {
        const unsigned* ap = adj2 + bs;
        unsigned j0 = ap[0], j1 = ap[1], j2 = ap[2], j3 = ap[3];
        unsigned j4 = ap[4], j5 = ap[5], j6 = ap[6], j7 = ap[7];
        unsigned o0 = (bs + 0 < re) ? (j0 << 3) : dummy_off;
        unsigned o1 = (bs + 1 < re) ? (j1 << 3) : dummy_off;
        unsigned o2 = (bs + 2 < re) ? (j2 << 3) : dummy_off;
        unsigned o3 = (bs + 3 < re) ? (j3 << 3) : dummy_off;
        unsigned o4 = (bs + 4 < re) ? (j4 << 3) : dummy_off;
        unsigned o5 = (bs + 5 < re) ? (j5 << 3) : dummy_off;
        unsigned o6 = (bs + 6 < re) ? (j6 << 3) : dummy_off;
        unsigned o7 = (bs + 7 < re) ? (j7 << 3) : dummy_off;
        GL2(w0, o0) GL2(w1, o1) GL2(w2, o2) GL2(w3, o3)
        GL2(w4, o4) GL2(w5, o5) GL2(w6, o6) GL2(w7, o7)
        asm volatile("s_waitcnt vmcnt(0)" ::: "memory");
        __builtin_amdgcn_sched_barrier(0);
        a0 += w0[0] + w1[0] + w2[0] + w3[0] + w4[0] + w5[0] + w6[0] + w7[0];
        a1 += w0[1] + w1[1] + w2[1] + w3[1] + w4[1] + w5[1] + w6[1] + w7[1];
    }
    const float2* h2p = (const float2*)hs2;
    float2 selfv = h2p[node];
    float dv = dinv[node];
    float2 r;
    r.x = fmaf(dv, a0 + selfv.x, b2[0]);
    r.y = fmaf(dv, a1 + selfv.y, b2[1]);
    out[node] = r;
}

// ---------- launcher ----------
extern "C" void kernel_launch(void* const* d_in, const int* in_sizes, int n_in,
                              void* d_out, int out_size, void* d_ws, size_t ws_size,
                              hipStream_t stream) {
    const float* x   = (const float*)d_in[0];
    const int*   ei  = (const int*)d_in[1];
    const int*   srcv = ei;
    const int*   dstv = ei + N_EDGES;
    const float* W1  = (const float*)d_in[2];
    const float* b1  = (const float*)d_in[3];
    const float* W2  = (const float*)d_in[4];
    const float* b2  = (const float*)d_in[5];
    float* out = (float*)d_out;

    char* w = (char*)d_ws;
    unsigned* adj        = (unsigned*)w;  w += (size_t)N_EDGES * 4;        // 12.8 MB
    unsigned* adj2       = (unsigned*)w;  w += (size_t)(N_EDGES + 8) * 4;  // 12.8 MB + pad
    unsigned* blockHist  = (unsigned*)w;  w += (size_t)NB * G * 4;         // 1.25 MB
    unsigned* total      = (unsigned*)w;  w += (size_t)NB * 4;
    unsigned* bucketBase = (unsigned*)w;  w += (size_t)(NB + 1) * 4;
    int*      rowstart   = (int*)w;       w += (size_t)(N_NODES + 1) * 4;  // 0.4 MB
    w = (char*)(((size_t)w + 15) & ~(size_t)15);
    float* dinv  = (float*)w;  w += (size_t)N_NODES * 4;                   // 0.4 MB
    char*  hs    = w;          w += (size_t)NPAD * HIDDEN * 2;             // 3.2 MB fp16
    float* hs2   = (float*)w;                                              // 0.8 MB

    k_hist        <<<G, 256, 0, stream>>>(dstv, blockHist);
    k_scan_blocks <<<NB, 1024, 0, stream>>>(blockHist, total);
    k_scan_buckets<<<1, 512, 0, stream>>>(total, bucketBase, rowstart);
    k_scatter     <<<G, 256, 0, stream>>>(srcv, dstv, blockHist, bucketBase, adj);
    k_sortmm      <<<NB, 512, 0, stream>>>(adj, bucketBase, x, W1, adj2, rowstart, dinv, hs);
    k_agg1        <<<(2 * NPAD) / 256, 256, 0, stream>>>(adj2, rowstart, hs, dinv,
                                                         b1, W2, (float2*)hs2);
    k_agg2        <<<(NPAD + 255) / 256, 256, 0, stream>>>(adj2, rowstart, (const char*)hs2,
                                                           dinv, b2, (float2*)out);
}